// Round 1
// baseline (580.251 us; speedup 1.0000x reference)
//
#include <hip/hip_runtime.h>

// EMA recurrence lta[t] = lta[t-1] + w*(x[t]-lta[t-1]) over [B=256, T=60000, C=3] fp32.
// Chunked with warm-up: influence of carry decays as (1-w)^n = 0.985^n; after 512
// steps the contribution is < 2.2e-4 absolute (max|y| ~ 0.5), far below the 8.98e-3
// threshold. Each thread owns one (b, c, chunk): runs 512 warm-up steps from y=0,
// then computes+stores its 512-element chunk. 90,624 threads = 1416 waves.

#define T_LEN 60000
#define BATCH 256
#define CH    3
#define CHUNK 512
#define WARM  512

__global__ __launch_bounds__(256) void lta_kernel(const float* __restrict__ x,
                                                  float* __restrict__ out,
                                                  int nC, int total) {
    int tid = blockIdx.x * blockDim.x + threadIdx.x;
    if (tid >= total) return;

    int c     = tid % CH;
    int chunk = (tid / CH) % nC;
    int b     = tid / (CH * nC);

    int t_start = chunk * CHUNK;
    int t_end   = t_start + CHUNK;
    if (t_end > T_LEN) t_end = T_LEN;
    int t_warm  = t_start - WARM;
    if (t_warm < 0) t_warm = 0;

    const float w = 0.015f;
    const float* __restrict__ px   = x   + (size_t)b * T_LEN * CH + c;
    float* __restrict__       pout = out + (size_t)b * T_LEN * CH + c;

    float y = 0.0f;

    // Warm-up: recover the carry to within 0.985^512 ~ 4.4e-4 relative.
    #pragma unroll 4
    for (int t = t_warm; t < t_start; ++t) {
        float xv = px[(size_t)t * CH];
        y = fmaf(w, xv - y, y);   // exact same formula as reference
    }

    // Main chunk: compute and store.
    #pragma unroll 4
    for (int t = t_start; t < t_end; ++t) {
        float xv = px[(size_t)t * CH];
        y = fmaf(w, xv - y, y);
        pout[(size_t)t * CH] = y;
    }
}

extern "C" void kernel_launch(void* const* d_in, const int* in_sizes, int n_in,
                              void* d_out, int out_size, void* d_ws, size_t ws_size,
                              hipStream_t stream) {
    const float* x = (const float*)d_in[0];
    float* out = (float*)d_out;

    const int nC = (T_LEN + CHUNK - 1) / CHUNK;        // 118
    const int total = BATCH * nC * CH;                 // 90624
    const int block = 256;
    const int grid = (total + block - 1) / block;      // 354

    lta_kernel<<<grid, block, 0, stream>>>(x, out, nC, total);
}